// Round 18
// baseline (566.893 us; speedup 1.0000x reference)
//
#include <hip/hip_runtime.h>
#include <hip/hip_bf16.h>

typedef __attribute__((ext_vector_type(8))) short short8;
typedef __attribute__((ext_vector_type(4))) float f32x4;

#define TWARM 96
#define SOUT  24
#define WIN   24   // x staging window (timesteps per per-wave LDS window)
#define XPS   25   // padded x_lds row stride in words (kills bank aliasing)
#define NWIN  (TWARM / WIN)
#define K1 1.44269504089f   // log2(e)
#define K2 2.88539008178f   // 2*log2(e)

// Intra-wave fence: LDS ordering AND (r14 lesson) a scheduler region boundary
// that stops cross-step hoisting from exploding live ranges.
#define LGKM_FENCE() do { \
    asm volatile("s_waitcnt lgkmcnt(0)" ::: "memory"); \
    __builtin_amdgcn_sched_barrier(0); \
} while (0)

static __device__ __forceinline__ short f2bf(float f) {
    __hip_bfloat16 h = __float2bfloat16(f);
    return *reinterpret_cast<short*>(&h);
}
static __device__ __forceinline__ float bf2f(short s) {
    unsigned u = ((unsigned)(unsigned short)s) << 16;
    return __builtin_bit_cast(float, u);
}
static __device__ __forceinline__ unsigned pkbf(float lo, float hi) {
    return (unsigned)(unsigned short)f2bf(lo)
         | ((unsigned)(unsigned short)f2bf(hi) << 16);
}

// r17 structure (x@W+b on the MFMA pipe; spill-free base at 64 VGPR) + the
// r12 2-chain idea, now viable: each wave runs TWO independent 16-row chains
// sharing every u-fragment ds_read (LDS traffic per row HALVED, fences
// amortized 2x). 512 thr = 8 waves x 32 rows = 256 rows/block; grid 256 =
// exactly 1 block/CU, zero tail. waves_per_eu(2,2) -> 256-reg budget, so the
// ~105-reg live set cannot spill (r12's failure mode eliminated).
__global__ void __attribute__((amdgpu_flat_work_group_size(512, 512),
                               amdgpu_waves_per_eu(2, 2)))
lstm_ar_kernel(const float* __restrict__ gin, const float* __restrict__ gW,
               const float* __restrict__ gU, const float* __restrict__ gb,
               const float* __restrict__ gWd, const float* __restrict__ gbd,
               float* __restrict__ gout, int B)
{
    __shared__ __align__(16) short    U_lds[16384];        // 32 KB: frag 0,1 (H@U)
    __shared__ __align__(16) short    U2_lds[2048];        // 4 KB: compact frag 2
    __shared__ __align__(16) short    h_lds[8][32][72];    // 36.9 KB, per-wave padded
    __shared__ __align__(16) unsigned x_lds[8][32][XPS];   // 25.6 KB bf16-pair x / preds
    __shared__ float wdc_lds[4][2][16];                    // 512 B

    const int tid  = threadIdx.x;
    const int wv   = tid >> 6;
    const int lane = tid & 63;
    const int c4   = lane & 15;   // MFMA col / A-row selector
    const int hi   = lane >> 4;   // MFMA k-group / C-row group

    // ---- stage U fragments 0,1 (H@U part; swizzled, gate-scale folded) ----
    for (int idx = tid; idx < 16384; idx += 512) {
        int k = idx >> 8, col = idx & 255;
        float sc = ((col >> 6) == 2) ? -K2 : -K1;   // g columns get -2*log2e
        int n = col >> 4, frag = k >> 5, sub = (k & 31) >> 3;
        int dst = (n * 2 + frag) * 512 + sub * 128 + (col & 15) * 8 + (k & 7);
        U_lds[dst] = f2bf(sc * gU[idx]);
    }
    // ---- stage compact U fragment 2: k_v 0->W0, 1->W1, 2->b, 3..7 -> 0 ----
    for (int i = tid; i < 2048; i += 512) {
        int n = i >> 7, cc = (i >> 3) & 15, e = i & 7;
        int col = n * 16 + cc;
        float sc = ((col >> 6) == 2) ? -K2 : -K1;
        float v = 0.f;
        if (e == 0)      v = sc * gW[col];
        else if (e == 1) v = sc * gW[256 + col];
        else if (e == 2) v = sc * gb[col];
        U2_lds[n * 128 + cc * 8 + e] = f2bf(v);
    }
    // ---- Wd table ----
    if (tid < 128) {
        int tt = tid >> 5, j = (tid >> 4) & 1, cc = tid & 15;
        wdc_lds[tt][j][cc] = gWd[(tt * 16 + cc) * 2 + j];
    }
    const float bd0 = gbd[0], bd1 = gbd[1];

    const int row0   = blockIdx.x * 256 + wv * 32;   // this wave's 32 rows
    const bool active = (row0 + 31) < B;

    // zero this wave's h buffer
    for (int i = lane; i < 32 * 72; i += 64) (&h_lds[wv][0][0])[i] = 0;

    // ---- per-wave x window staging: 32 rows x WIN steps, bf16 pairs ----
    const int xrow = lane >> 1, xq = lane & 1;   // 2 lanes/row, 24 floats each
    auto stage_x = [&](int w) {
        const float* src = gin + (size_t)(row0 + xrow) * (TWARM * 2)
                         + w * (WIN * 2) + xq * 24;
#pragma unroll
        for (int m = 0; m < 6; ++m) {
            float4 v = *reinterpret_cast<const float4*>(src + m * 4);
            x_lds[wv][xrow][xq * 12 + m * 2 + 0] = pkbf(v.x, v.y);
            x_lds[wv][xrow][xq * 12 + m * 2 + 1] = pkbf(v.z, v.w);
        }
        LGKM_FENCE();   // window visible to this wave before first read
    };

    if (active) stage_x(0);
    __syncthreads();    // the ONLY block barrier: U + U2 + wdc staged & visible
    if (!active) return;

    float c_[2][4][4];  // pre-scaled: c' = -K2 * c ; [chain][tt][r]
#pragma unroll
    for (int ch = 0; ch < 2; ++ch)
#pragma unroll
        for (int tt = 0; tt < 4; ++tt)
#pragma unroll
            for (int r = 0; r < 4; ++r) c_[ch][tt][r] = 0.f;

    const short* hbase = &h_lds[wv][0][0];
    const short* hptr  = hbase + c4 * 72 + hi * 8;               // chain A A-frag base
    short*       hwptr = &h_lds[wv][0][0] + (hi * 4) * 72 + c4;  // chain A h write base
    const short* uptr  = U_lds + lane * 8;                       // B-frag read base
    const short* uptr2 = U2_lds + c4 * 8;       // compact frag 2 (hi groups broadcast)
    // chain B: +16 rows = +1152 shorts on hptr/hwptr

    const f32x4 zero4 = {0.f, 0.f, 0.f, 0.f};
    float h_[2][4][4];  // live during decode only

    // ---- one LSTM step for BOTH chains; u-frag reads shared ----
    auto lstm_step = [&](unsigned xpA, unsigned xpB, bool save_h) {
        short8 aA0 = *reinterpret_cast<const short8*>(hptr);
        short8 aA1 = *reinterpret_cast<const short8*>(hptr + 32);
        short8 aB0 = *reinterpret_cast<const short8*>(hptr + 1152);
        short8 aB1 = *reinterpret_cast<const short8*>(hptr + 1184);
        short8 a2A = {0, 0, 0, 0, 0, 0, 0, 0};   // virtual K-rows {x0, x1, 1}
        short8 a2B = {0, 0, 0, 0, 0, 0, 0, 0};
        if (hi == 0) {
            a2A[0] = (short)(xpA & 0xFFFFu);
            a2A[1] = (short)(xpA >> 16);
            a2A[2] = (short)0x3F80;
            a2B[0] = (short)(xpB & 0xFFFFu);
            a2B[1] = (short)(xpB >> 16);
            a2B[2] = (short)0x3F80;
        }
#pragma unroll
        for (int tt = 0; tt < 4; ++tt) {
            f32x4 accA[4], accB[4];   // tiles n = tt+4j -> i,f,g,o
#pragma unroll
            for (int j = 0; j < 4; ++j) {
                const int n = tt + 4 * j;
                short8 u2 = *reinterpret_cast<const short8*>(uptr2 + n * 128);
                accA[j] = __builtin_amdgcn_mfma_f32_16x16x32_bf16(a2A, u2, zero4, 0, 0, 0);
                accB[j] = __builtin_amdgcn_mfma_f32_16x16x32_bf16(a2B, u2, zero4, 0, 0, 0);
            }
#pragma unroll
            for (int j = 0; j < 4; ++j) {
                const int n = tt + 4 * j;
                short8 u0 = *reinterpret_cast<const short8*>(uptr + (n * 2 + 0) * 512);
                short8 u1 = *reinterpret_cast<const short8*>(uptr + (n * 2 + 1) * 512);
                accA[j] = __builtin_amdgcn_mfma_f32_16x16x32_bf16(aA0, u0, accA[j], 0, 0, 0);
                accA[j] = __builtin_amdgcn_mfma_f32_16x16x32_bf16(aA1, u1, accA[j], 0, 0, 0);
                accB[j] = __builtin_amdgcn_mfma_f32_16x16x32_bf16(aB0, u0, accB[j], 0, 0, 0);
                accB[j] = __builtin_amdgcn_mfma_f32_16x16x32_bf16(aB1, u1, accB[j], 0, 0, 0);
            }
            // gates per chain: ea=e^{-zi}, ef=e^{-zf}, eg=e^{-2zg}, eo=e^{-zo}
#pragma unroll
            for (int ch = 0; ch < 2; ++ch) {
#pragma unroll
                for (int r = 0; r < 4; ++r) {
                    const f32x4* ac = ch ? accB : accA;
                    float ea = __builtin_amdgcn_exp2f(ac[0][r]);
                    float ef = __builtin_amdgcn_exp2f(ac[1][r]);
                    float eg = __builtin_amdgcn_exp2f(ac[2][r]);
                    float eo = __builtin_amdgcn_exp2f(ac[3][r]);
                    float sf = __builtin_amdgcn_rcpf(1.0f + ef);
                    float sg = fmaf(eg, K2, -K2) *
                        __builtin_amdgcn_rcpf((1.0f + ea) * (1.0f + eg));
                    float cn = fmaf(sf, c_[ch][tt][r], sg);
                    c_[ch][tt][r] = cn;
                    float ec = __builtin_amdgcn_exp2f(cn);
                    float hn = (1.0f - ec) *
                        __builtin_amdgcn_rcpf((1.0f + eo) * (1.0f + ec));
                    if (save_h) h_[ch][tt][r] = hn;
                    hwptr[ch * 1152 + r * 72 + tt * 16] = f2bf(hn);
                }
            }
        }
        LGKM_FENCE();   // h writes ordered before next step + sched region cap
    };

    // ---- warmup: 96 steps, x from this wave's LDS windows (2 reads/step) ----
#pragma unroll 1
    for (int w = 0; w < NWIN; ++w) {
        if (w != 0) stage_x(w);   // prior step's fence ordered old-window reads
#pragma unroll 1
        for (int tl = 0; tl < WIN; ++tl)
            lstm_step(x_lds[wv][c4][tl], x_lds[wv][16 + c4][tl], false);
    }

    // rebuild h_ (f32) from the bf16 LDS copy once after warmup
#pragma unroll
    for (int ch = 0; ch < 2; ++ch)
#pragma unroll
        for (int tt = 0; tt < 4; ++tt)
#pragma unroll
            for (int r = 0; r < 4; ++r)
                h_[ch][tt][r] =
                    bf2f(hbase[(ch * 16 + hi * 4 + r) * 72 + tt * 16 + c4]);

    // hoist Wd for this lane's cols (decode-only registers)
    float wdc[4][2];
#pragma unroll
    for (int tt = 0; tt < 4; ++tt) {
        wdc[tt][0] = wdc_lds[tt][0][c4];
        wdc[tt][1] = wdc_lds[tt][1][c4];
    }

    // ---- decode: pred = h@Wd + bd per chain, butterfly over 16-lane groups ----
    auto make_pred = [&](int ch, float* p0, float* p1) {
#pragma unroll
        for (int r = 0; r < 4; ++r) {
            float a0 = 0.f, a1 = 0.f;
#pragma unroll
            for (int tt = 0; tt < 4; ++tt) {
                a0 = fmaf(h_[ch][tt][r], wdc[tt][0], a0);
                a1 = fmaf(h_[ch][tt][r], wdc[tt][1], a1);
            }
            p0[r] = a0; p1[r] = a1;
        }
#pragma unroll
        for (int m = 1; m < 16; m <<= 1)
#pragma unroll
            for (int r = 0; r < 4; ++r) {
                p0[r] += __shfl_xor(p0[r], m, 64);
                p1[r] += __shfl_xor(p1[r], m, 64);
            }
#pragma unroll
        for (int r = 0; r < 4; ++r) { p0[r] += bd0; p1[r] += bd1; }
    };
    // fetch row c4's pred from the lane group that owns it; pack bf16 pair
    auto build_xp = [&](const float* p0, const float* p1) -> unsigned {
        int srcl = (c4 >> 2) << 4;   // lane with hi = c4>>2 (col 0 of its group)
        float a  = __shfl(p0[0], srcl, 64), b2 = __shfl(p0[1], srcl, 64);
        float cc = __shfl(p0[2], srcl, 64), d  = __shfl(p0[3], srcl, 64);
        float e  = __shfl(p1[0], srcl, 64), f  = __shfl(p1[1], srcl, 64);
        float g  = __shfl(p1[2], srcl, 64), h2 = __shfl(p1[3], srcl, 64);
        int rr = c4 & 3;
        float q0 = (rr & 2) ? ((rr & 1) ? d  : cc) : ((rr & 1) ? b2 : a);
        float q1 = (rr & 2) ? ((rr & 1) ? h2 : g)  : ((rr & 1) ? f  : e);
        return pkbf(q0, q1);
    };
    // stash pred bf16 in this wave's (dead) x window for the final writeout
    auto store_pred = [&](int ch, int s, const float* p0, const float* p1) {
        if (c4 == 0) {
#pragma unroll
            for (int r = 0; r < 4; ++r)
                x_lds[wv][ch * 16 + hi * 4 + r][s] = pkbf(p0[r], p1[r]);
        }
    };

    float pA0[4], pA1[4], pB0[4], pB1[4];
    make_pred(0, pA0, pA1);
    make_pred(1, pB0, pB1);
    store_pred(0, 0, pA0, pA1);
    store_pred(1, 0, pB0, pB1);
#pragma unroll 1
    for (int s = 1; s < SOUT; ++s) {
        lstm_step(build_xp(pA0, pA1), build_xp(pB0, pB1), true);
        make_pred(0, pA0, pA1);
        make_pred(1, pB0, pB1);
        store_pred(0, s, pA0, pA1);
        store_pred(1, s, pB0, pB1);
    }
    LGKM_FENCE();   // all pred stashes of this wave visible to this wave

    // ---- per-wave coalesced writeout: 32 rows x 48 floats ----
#pragma unroll
    for (int m = 0; m < 12; ++m) {
        unsigned u = x_lds[wv][xrow][xq * 12 + m];
        *reinterpret_cast<float2*>(
            gout + (size_t)(row0 + xrow) * (SOUT * 2) + (xq * 12 + m) * 2) =
            make_float2(bf2f((short)(u & 0xFFFFu)), bf2f((short)(u >> 16)));
    }
}

extern "C" void kernel_launch(void* const* d_in, const int* in_sizes, int n_in,
                              void* d_out, int out_size, void* d_ws, size_t ws_size,
                              hipStream_t stream) {
    const float* gin  = (const float*)d_in[0];
    const float* gW   = (const float*)d_in[1];
    const float* gU   = (const float*)d_in[2];
    const float* gb   = (const float*)d_in[3];
    const float* gWd  = (const float*)d_in[4];
    const float* gbd  = (const float*)d_in[5];
    float* gout = (float*)d_out;

    const int B = in_sizes[0] / (TWARM * 2);
    const int blocks = (B + 255) / 256;
    lstm_ar_kernel<<<blocks, 512, 0, stream>>>(gin, gW, gU, gb, gWd, gbd, gout, B);
}